// Round 2
// baseline (435.649 us; speedup 1.0000x reference)
//
#include <hip/hip_runtime.h>

// Depthwise 1D conv (cross-correlation), SAME padding (pad_left = 4).
// x: (B=8, F=64, L=131072) f32 ; kernel: (F, 1, K=9) f32
// out: (F, B, 1, L) f32 -> out[(f*B + b)*L + l]
//
// One block per 1024-element row chunk. Stage chunk + 8-elem halo (1032
// floats) into LDS via exactly-once aligned float4 loads, compute 4 outputs
// per thread from LDS, one float4 store. Global traffic = 1.008x read + 1x
// write — the memory-bound minimum.

#define BB 8
#define FF 64
#define LL 131072
#define KK 9
#define CHUNK 1024
#define CPR (LL / CHUNK)      // 128 chunks per row
#define CPR_SHIFT 7
#define NROWS (BB * FF)       // 512
#define LDS_N (CHUNK + 8)     // 1032 floats staged (x[l0-4 .. l0+1027])

__global__ __launch_bounds__(256) void dwconv1d_kernel(
    const float* __restrict__ x,
    const float* __restrict__ kern,
    float* __restrict__ out)
{
    __shared__ float s[LDS_N];

    const int c       = blockIdx.x;
    const int chunk   = c & (CPR - 1);
    const int row_out = c >> CPR_SHIFT;   // f*8 + b, in [0, 512)
    const int f       = row_out >> 3;
    const int b       = row_out & 7;

    const float* xrow = x + ((size_t)(b * FF + f)) * (size_t)LL;
    const int l0 = chunk << 10;           // chunk * 1024
    const int t  = threadIdx.x;

    // Stage s[j] = x[l0 - 4 + j], j in [0, 1032), zero outside [0, L).
    // 258 aligned float4 loads; l0-4 is 4-aligned so no straddle: each
    // float4 is either fully in-bounds or fully out (only at row edges).
    #pragma unroll
    for (int v = t; v < LDS_N / 4; v += 256) {
        const int g = l0 - 4 + 4 * v;     // global float index of s[4v..4v+3]
        float4 val = make_float4(0.f, 0.f, 0.f, 0.f);
        if (g >= 0 && g + 3 < LL) val = *(const float4*)(xrow + g);
        *(float4*)(&s[4 * v]) = val;
    }

    // Weights: f is block-uniform -> scalar loads, L1/K$ resident.
    float w[KK];
    #pragma unroll
    for (int k = 0; k < KK; ++k) w[k] = kern[f * KK + k];

    __syncthreads();

    // Thread t computes outputs l0 + 4t .. 4t+3:
    //   out[l0+4t+j] = sum_k w[k] * x[l0+4t+j-4+k] = sum_k w[k]*s[4t+j+k]
    float xin[12];
    #pragma unroll
    for (int m = 0; m < 12; ++m) xin[m] = s[4 * t + m];

    float acc[4];
    #pragma unroll
    for (int j = 0; j < 4; ++j) {
        float v0 = 0.f;
        #pragma unroll
        for (int k = 0; k < KK; ++k) v0 += w[k] * xin[j + k];
        acc[j] = v0;
    }

    float4 o = make_float4(acc[0], acc[1], acc[2], acc[3]);
    *(float4*)(out + (size_t)row_out * (size_t)LL + l0 + 4 * t) = o;
}

extern "C" void kernel_launch(void* const* d_in, const int* in_sizes, int n_in,
                              void* d_out, int out_size, void* d_ws, size_t ws_size,
                              hipStream_t stream) {
    const float* x    = (const float*)d_in[0];
    const float* kern = (const float*)d_in[1];
    float* out        = (float*)d_out;

    const int grid  = NROWS * CPR;   // 65,536 blocks
    const int block = 256;

    hipLaunchKernelGGL(dwconv1d_kernel, dim3(grid), dim3(block), 0, stream,
                       x, kern, out);
}